// Round 13
// baseline (282.080 us; speedup 1.0000x reference)
//
#include <hip/hip_runtime.h>
#include <hip/hip_bf16.h>

// ---- problem constants ----
#define NN 25000
#define PP 100000
#define TT 4
#define DD 128
#define LEAKY 0.001f

#define PB 32          // propers per block
#define ROWS 128       // PB * TT rows of the MLP per block

typedef __bf16 bf16;
typedef __bf16 bf16x8 __attribute__((ext_vector_type(8)));
typedef float  f32x4  __attribute__((ext_vector_type(4)));

// ---- workspace layout (bytes) ----
#define OFF_W0SW  0u                    // 128 chunks * 1KB (fragment order)
#define OFF_W1SW  131072u               // 32 chunks * 1KB
#define OFF_W2SW  163840u               // 32 chunks * 1KB
#define OFF_W3SW  196608u               // 4 chunks * 1KB
#define OFF_WTB   200704u               // Wt[t][j] = t*W0[512]+b0, 4*128 bf16
#define OFF_W5B   201728u               // W0 rows 513..515 as bf16
#define OFF_E     202496u               // 4 tables [NN][128] bf16 = 25,600,000 B
#define WS_END    25802496u

// prep work partition (thread counts)
#define PR_W0SW  65536
#define PR_W1SW  16384
#define PR_W2SW  16384
#define PR_W3SW  2048
#define PR_WTB   512
#define PR_W5B   384
#define PR_COPY4 75000
#define PR_TOTAL (PR_W0SW + PR_W1SW + PR_W2SW + PR_W3SW + PR_WTB + PR_W5B + PR_COPY4)

__global__ __launch_bounds__(256) void prep_kernel(
    const float* __restrict__ W0, const float* __restrict__ W1,
    const float* __restrict__ W2, const float* __restrict__ W3,
    const float* __restrict__ answer, const float* __restrict__ tvec,
    const float* __restrict__ b0,
    bf16* __restrict__ W0sw, bf16* __restrict__ W1sw, bf16* __restrict__ W2sw,
    bf16* __restrict__ W3sw, bf16* __restrict__ WtB, bf16* __restrict__ W5B,
    float* __restrict__ out)
{
    int idx = blockIdx.x * 256 + threadIdx.x;
    if (idx < PR_W0SW) {
        int j = idx & 7, lane = (idx >> 3) & 63, c = idx >> 9;
        int fr = lane & 15, quad = lane >> 4;
        int kc = c & 15, iwv = c >> 4;
        int k = kc * 32 + quad * 8 + j;
        W0sw[idx] = (bf16)W0[k * 128 + iwv * 16 + fr];
        return;
    }
    idx -= PR_W0SW;
    if (idx < PR_W1SW) {
        int j = idx & 7, lane = (idx >> 3) & 63, c = idx >> 9;
        int fr = lane & 15, quad = lane >> 4;
        int kc = c & 3, nt = c >> 2;
        int k = kc * 32 + quad * 8 + j;
        W1sw[idx] = (bf16)W1[k * 128 + nt * 16 + fr];
        return;
    }
    idx -= PR_W1SW;
    if (idx < PR_W2SW) {
        int j = idx & 7, lane = (idx >> 3) & 63, c = idx >> 9;
        int fr = lane & 15, quad = lane >> 4;
        int kc = c & 3, nt = c >> 2;
        int k = kc * 32 + quad * 8 + j;
        W2sw[idx] = (bf16)W2[k * 128 + nt * 16 + fr];
        return;
    }
    idx -= PR_W2SW;
    if (idx < PR_W3SW) {
        int j = idx & 7, lane = (idx >> 3) & 63, kc = idx >> 9;
        int fr = lane & 15, quad = lane >> 4;
        int k = kc * 32 + quad * 8 + j;
        W3sw[idx] = (fr < 2) ? (bf16)W3[k * 2 + fr] : (bf16)0.0f;
        return;
    }
    idx -= PR_W3SW;
    if (idx < PR_WTB) {                 // Wt[t][j] = tvec[t]*W0[512][j] + b0[j]
        int t = idx >> 7, j = idx & 127;
        WtB[idx] = (bf16)(tvec[t] * W0[512 * 128 + j] + b0[j]);
        return;
    }
    idx -= PR_WTB;
    if (idx < PR_W5B) {                 // W0 rows 513,514,515 -> bf16
        W5B[idx] = (bf16)W0[(513 + (idx >> 7)) * 128 + (idx & 127)];
        return;
    }
    idx -= PR_W5B;
    if (idx < PR_COPY4) { ((float4*)out)[idx] = ((const float4*)answer)[idx]; }
}

// E_i[n][j] = sum_k enc[n][k]*W0[i*128+k][j]. Grid 196x4 = 784 blocks.
__global__ __launch_bounds__(512) void prep_e_kernel(
    const float* __restrict__ encoded, const bf16* __restrict__ W0sw,
    bf16* __restrict__ E)
{
    __shared__ bf16 sA[128][136];
    __shared__ bf16 sT[128][40];
    const int tid = threadIdx.x;
    const int row0 = (blockIdx.x >> 2) * 128;
    const int ntb  = blockIdx.x & 3;
    for (int c = tid; c < 4096; c += 512) {      // 128 rows x 32 float4
        int row = c >> 5, seg = c & 31;
        int rr = row0 + row; if (rr >= NN) rr = NN - 1;
        float4 v = *(const float4*)(encoded + (size_t)rr * 128 + seg * 4);
        bf16 pk[4] = {(bf16)v.x, (bf16)v.y, (bf16)v.z, (bf16)v.w};
        *(uint2*)(&sA[row][seg * 4]) = *(const uint2*)pk;
    }
    __syncthreads();
    const int wv = tid >> 6, lane = tid & 63;
    const int fr = lane & 15, quad = lane >> 4;
    const bf16* aBase = &sA[wv * 16 + fr][quad * 8];
    bf16x8 aFv[4];
    #pragma unroll
    for (int kcc = 0; kcc < 4; ++kcc) aFv[kcc] = *(const bf16x8*)(aBase + kcc * 32);
    const int orow = tid >> 2, oseg = tid & 3;
    #pragma unroll
    for (int i = 0; i < 4; ++i) {
        #pragma unroll
        for (int ntl = 0; ntl < 2; ++ntl) {
            int nt = ntb * 2 + ntl;
            f32x4 acc = {0.f, 0.f, 0.f, 0.f};
            #pragma unroll
            for (int kcc = 0; kcc < 4; ++kcc) {
                bf16x8 bF = *(const bf16x8*)(W0sw + ((size_t)nt * 16 + i * 4 + kcc) * 512 + lane * 8);
                acc = __builtin_amdgcn_mfma_f32_16x16x32_bf16(aFv[kcc], bF, acc, 0, 0, 0);
            }
            #pragma unroll
            for (int reg = 0; reg < 4; ++reg)
                sT[wv * 16 + quad * 4 + reg][ntl * 16 + fr] = (bf16)acc[reg];
        }
        __syncthreads();
        if (row0 + orow < NN)
            *(bf16x8*)(E + ((size_t)i * NN + row0 + orow) * 128 + ntb * 32 + oseg * 8) =
                *(const bf16x8*)(&sT[orow][oseg * 8]);
        __syncthreads();
    }
}

// Main: MFMA operand order SWAPPED for layer GEMMs (A = W^T frags, B = H
// rows; identical fragment layouts so the existing Wsw tables serve as A).
// Output mapping flips: lane's 4 regs = 4 consecutive j of ONE row ->
// epilogue is one packed b64 LDS store instead of 4 scalar b16 (4x fewer
// LDS ops), bias via one float4 load. W2 frags reload into the dead wf regs
// after phase 3's MFMA so their latency hides behind epilogue + B3.
__global__ __launch_bounds__(512, 4) void main_kernel(
    const float* __restrict__ coords, const int* __restrict__ propers,
    const float* __restrict__ b1, const float* __restrict__ b2,
    const float* __restrict__ b3,
    const bf16* __restrict__ E, const bf16* __restrict__ W1sw,
    const bf16* __restrict__ W2sw, const bf16* __restrict__ W3sw,
    const bf16* __restrict__ WtB, const bf16* __restrict__ W5B,
    float* __restrict__ out)
{
    __shared__ bf16 sBuf0[ROWS * 136];   // H0 then H2
    __shared__ bf16 sBuf1[ROWS * 136];   // H1
    #define SH0(r, j) sBuf0[(r) * 136 + (j)]
    #define SH1(r, j) sBuf1[(r) * 136 + (j)]
    __shared__ int   sNodes[PB][4];
    __shared__ float sSn[ROWS], sCs[ROWS], sDl[ROWS], sDh[ROWS][3];
    __shared__ float sDelta[ROWS][2];

    const int tid  = threadIdx.x;
    const int pBase = blockIdx.x * PB;
    const int wv = tid >> 6, lane = tid & 63;
    const int fr = lane & 15, quad = lane >> 4;
    const int m2 = (wv & 3) * 2;   // first of 2 row-tiles for phases 3/4
    const int nh = wv >> 2;        // N-half (cols nh*64..+63)

    // ---- phase 1: E gather + W1-frag prefetch (all 512) + geometry (tid<128) ----
    const int p  = tid >> 4, s8 = tid & 15;          // 16 threads per proper
    bf16x8 e0, e1, e2, e3;
    {
        int4 pv = *(const int4*)(propers + (pBase + p) * 4);
        if (s8 == 0) { sNodes[p][0] = pv.x; sNodes[p][1] = pv.y;
                       sNodes[p][2] = pv.z; sNodes[p][3] = pv.w; }
        e0 = *(const bf16x8*)(E + ((size_t)0 * NN + pv.x) * 128 + s8 * 8);
        e1 = *(const bf16x8*)(E + ((size_t)1 * NN + pv.y) * 128 + s8 * 8);
        e2 = *(const bf16x8*)(E + ((size_t)2 * NN + pv.z) * 128 + s8 * 8);
        e3 = *(const bf16x8*)(E + ((size_t)3 * NN + pv.w) * 128 + s8 * 8);
    }
    // wf: W1 A-frags for phase 3 (reloaded with W2 after phase 3).
    bf16x8 wf[16];
    {
        const bf16* w1b = W1sw + lane * 8;
        #pragma unroll
        for (int nt = 0; nt < 4; ++nt)
            #pragma unroll
            for (int kc = 0; kc < 4; ++kc)
                wf[nt * 4 + kc] = *(const bf16x8*)(w1b + ((nh * 4 + nt) * 4 + kc) * 512);
    }
    if (tid < ROWS) {
        int r = tid, pp = r >> 2, t = r & 3;
        int4 pv = *(const int4*)(propers + (pBase + pp) * 4);
        const float* c0 = coords + pv.x * 12 + t * 3;
        const float* c1 = coords + pv.y * 12 + t * 3;
        const float* c2 = coords + pv.z * 12 + t * 3;
        const float* c3 = coords + pv.w * 12 + t * 3;
        float u1x = c1[0]-c0[0], u1y = c1[1]-c0[1], u1z = c1[2]-c0[2];
        float u2x = c2[0]-c1[0], u2y = c2[1]-c1[1], u2z = c2[2]-c1[2];
        float u3x = c3[0]-c2[0], u3y = c3[1]-c2[1], u3z = c3[2]-c2[2];
        float ax = u1y*u2z - u1z*u2y, ay = u1z*u2x - u1x*u2z, az = u1x*u2y - u1y*u2x;
        float bx = u2y*u3z - u2z*u3y, by = u2z*u3x - u2x*u3z, bz = u2x*u3y - u2y*u3x;
        float u2n = sqrtf(u2x*u2x + u2y*u2y + u2z*u2z);
        float num = u2n * (u1x*bx + u1y*by + u1z*bz);
        float den = ax*bx + ay*by + az*bz;
        float hyp = sqrtf(num*num + den*den);
        float sn, cs;
        if (hyp > 1e-30f) { float ih = 1.0f / hyp; sn = num * ih; cs = den * ih; }
        else { sn = 0.0f; cs = 1.0f; }
        float drx = c0[0]-c3[0], dry = c0[1]-c3[1], drz = c0[2]-c3[2];
        float dl = sqrtf(fmaxf(drx*drx + dry*dry + drz*drz, 1e-12f));
        float il = 1.0f / dl;
        sSn[r] = sn; sCs[r] = cs; sDl[r] = dl;
        sDh[r][0] = drx * il; sDh[r][1] = dry * il; sDh[r][2] = drz * il;
    }
    __syncthreads();   // B1: geometry + all phase-1 loads drained

    // ---- h0 = leaky(g + Wt[t] + sn*w513 + cs*w514 + dl*w515) -> SH0 ----
    {
        float g[8], w3f[8], w4f[8], w5f[8];
        #pragma unroll
        for (int j = 0; j < 8; ++j)
            g[j] = (float)e0[j] + (float)e1[j] + (float)e2[j] + (float)e3[j];
        bf16x8 w3v = *(const bf16x8*)(W5B + 0 * 128 + s8 * 8);
        bf16x8 w4v = *(const bf16x8*)(W5B + 1 * 128 + s8 * 8);
        bf16x8 w5v = *(const bf16x8*)(W5B + 2 * 128 + s8 * 8);
        #pragma unroll
        for (int j = 0; j < 8; ++j) {
            w3f[j] = (float)w3v[j]; w4f[j] = (float)w4v[j]; w5f[j] = (float)w5v[j];
        }
        #pragma unroll
        for (int t = 0; t < 4; ++t) {
            int r = p * 4 + t;
            bf16x8 wtv = *(const bf16x8*)(WtB + t * 128 + s8 * 8);
            float sn = sSn[r], cs = sCs[r], dl = sDl[r];
            bf16 hv[8];
            #pragma unroll
            for (int j = 0; j < 8; ++j) {
                float v = g[j] + (float)wtv[j] + sn * w3f[j] + cs * w4f[j] + dl * w5f[j];
                v = fmaxf(v, LEAKY * v);
                hv[j] = (bf16)v;
            }
            *(bf16x8*)(&SH0(r, s8 * 8)) = *(const bf16x8*)hv;
        }
    }
    __syncthreads();   // B2: H0 ready

    // ---- phase 3: h1 = leaky(h0 @ W1 + b1); A=wf (W1^T), B=H0 rows ----
    #pragma unroll
    for (int s = 0; s < 2; ++s) {
        f32x4 hacc[4];
        #pragma unroll
        for (int nt = 0; nt < 4; ++nt) hacc[nt] = (f32x4){0.f,0.f,0.f,0.f};
        const bf16* bRow = &SH0((m2 + s) * 16 + fr, quad * 8);
        #pragma unroll
        for (int kc = 0; kc < 4; ++kc) {
            bf16x8 bF = *(const bf16x8*)(bRow + kc * 32);
            #pragma unroll
            for (int nt = 0; nt < 4; ++nt)
                hacc[nt] = __builtin_amdgcn_mfma_f32_16x16x32_bf16(wf[nt * 4 + kc], bF, hacc[nt], 0, 0, 0);
        }
        int r = (m2 + s) * 16 + fr;          // D col = H row
        #pragma unroll
        for (int nt = 0; nt < 4; ++nt) {
            int j0 = (nh * 4 + nt) * 16 + quad * 4;   // D rows = 4 consecutive j
            float4 bb = *(const float4*)(b1 + j0);
            bf16 hv[4];
            float v0 = hacc[nt][0] + bb.x; v0 = fmaxf(v0, LEAKY * v0); hv[0] = (bf16)v0;
            float v1 = hacc[nt][1] + bb.y; v1 = fmaxf(v1, LEAKY * v1); hv[1] = (bf16)v1;
            float v2 = hacc[nt][2] + bb.z; v2 = fmaxf(v2, LEAKY * v2); hv[2] = (bf16)v2;
            float v3 = hacc[nt][3] + bb.w; v3 = fmaxf(v3, LEAKY * v3); hv[3] = (bf16)v3;
            *(uint2*)(&SH1(r, j0)) = *(const uint2*)hv;
        }
    }
    // reload wf <- W2 frags; latency hides behind epilogue + B3
    {
        const bf16* w2b = W2sw + lane * 8;
        #pragma unroll
        for (int nt = 0; nt < 4; ++nt)
            #pragma unroll
            for (int kc = 0; kc < 4; ++kc)
                wf[nt * 4 + kc] = *(const bf16x8*)(w2b + ((nh * 4 + nt) * 4 + kc) * 512);
    }
    __syncthreads();   // B3: H1 ready, H0 reads complete

    // ---- phase 4: h2 = leaky(h1 @ W2 + b2); A=wf (W2^T), B=H1 rows ----
    #pragma unroll
    for (int s = 0; s < 2; ++s) {
        f32x4 hacc[4];
        #pragma unroll
        for (int nt = 0; nt < 4; ++nt) hacc[nt] = (f32x4){0.f,0.f,0.f,0.f};
        const bf16* bRow = &SH1((m2 + s) * 16 + fr, quad * 8);
        #pragma unroll
        for (int kc = 0; kc < 4; ++kc) {
            bf16x8 bF = *(const bf16x8*)(bRow + kc * 32);
            #pragma unroll
            for (int nt = 0; nt < 4; ++nt)
                hacc[nt] = __builtin_amdgcn_mfma_f32_16x16x32_bf16(wf[nt * 4 + kc], bF, hacc[nt], 0, 0, 0);
        }
        int r = (m2 + s) * 16 + fr;
        #pragma unroll
        for (int nt = 0; nt < 4; ++nt) {
            int j0 = (nh * 4 + nt) * 16 + quad * 4;
            float4 bb = *(const float4*)(b2 + j0);
            bf16 hv[4];
            float v0 = hacc[nt][0] + bb.x; v0 = fmaxf(v0, LEAKY * v0); hv[0] = (bf16)v0;
            float v1 = hacc[nt][1] + bb.y; v1 = fmaxf(v1, LEAKY * v1); hv[1] = (bf16)v1;
            float v2 = hacc[nt][2] + bb.z; v2 = fmaxf(v2, LEAKY * v2); hv[2] = (bf16)v2;
            float v3 = hacc[nt][3] + bb.w; v3 = fmaxf(v3, LEAKY * v3); hv[3] = (bf16)v3;
            *(uint2*)(&SH0(r, j0)) = *(const uint2*)hv;
        }
    }
    __syncthreads();   // B4: H2 ready

    // ---- phase 5: delta = h2 @ W3 + b3; A=W3^T frags, B=H2 rows ----
    {
        f32x4 dacc = {0.f,0.f,0.f,0.f};
        const bf16* bRow = &SH0(wv * 16 + fr, quad * 8);
        const bf16* w3b = W3sw + lane * 8;
        #pragma unroll
        for (int kc = 0; kc < 4; ++kc) {
            bf16x8 aF = *(const bf16x8*)(w3b + kc * 512);
            bf16x8 bF = *(const bf16x8*)(bRow + kc * 32);
            dacc = __builtin_amdgcn_mfma_f32_16x16x32_bf16(aF, bF, dacc, 0, 0, 0);
        }
        if (quad == 0) {               // D rows 0,1 (= delta cols) live in regs 0,1
            int r = wv * 16 + fr;
            sDelta[r][0] = dacc[0] + b3[0];
            sDelta[r][1] = dacc[1] + b3[1];
        }
    }
    __syncthreads();   // B5: delta ready

    // ---- phase 6: scatter-add (6 atomics per row, 768 total) ----
    for (int idx = tid; idx < ROWS * 6; idx += 512) {
        int r = idx / 6, c = idx % 6;
        int pp = r >> 2, t = r & 3;
        int side = c / 3, ax = c % 3;
        int node = sNodes[pp][side ? 3 : 0];
        float dval = side ? 0.5f * sDelta[r][1] : -0.5f * sDelta[r][0];
        atomicAdd(out + node * 12 + t * 3 + ax, dval * sDh[r][ax]);
    }
    #undef SH0
    #undef SH1
}

extern "C" void kernel_launch(void* const* d_in, const int* in_sizes, int n_in,
                              void* d_out, int out_size, void* d_ws, size_t ws_size,
                              hipStream_t stream) {
    const float* coords  = (const float*)d_in[0];
    const int*   propers = (const int*)d_in[1];
    const float* encoded = (const float*)d_in[2];
    const float* tvec    = (const float*)d_in[3];
    const float* answer  = (const float*)d_in[4];
    const float* W0 = (const float*)d_in[5];
    const float* b0 = (const float*)d_in[6];
    const float* W1 = (const float*)d_in[7];
    const float* b1 = (const float*)d_in[8];
    const float* W2 = (const float*)d_in[9];
    const float* b2 = (const float*)d_in[10];
    const float* W3 = (const float*)d_in[11];
    const float* b3 = (const float*)d_in[12];
    float* out = (float*)d_out;
    char* ws = (char*)d_ws;
    bf16* W0sw = (bf16*)(ws + OFF_W0SW);
    bf16* W1sw = (bf16*)(ws + OFF_W1SW);
    bf16* W2sw = (bf16*)(ws + OFF_W2SW);
    bf16* W3sw = (bf16*)(ws + OFF_W3SW);
    bf16* WtB  = (bf16*)(ws + OFF_WTB);
    bf16* W5B  = (bf16*)(ws + OFF_W5B);
    bf16* E    = (bf16*)(ws + OFF_E);

    int prep_blocks = (PR_TOTAL + 255) / 256;
    prep_kernel<<<prep_blocks, 256, 0, stream>>>(W0, W1, W2, W3, answer, tvec, b0,
                                                 W0sw, W1sw, W2sw, W3sw, WtB, W5B, out);
    prep_e_kernel<<<196 * 4, 512, 0, stream>>>(encoded, W0sw, E);
    main_kernel<<<PP / PB, 512, 0, stream>>>(coords, propers, b1, b2, b3,
                                             E, W1sw, W2sw, W3sw, WtB, W5B, out);
}

// Round 14
// 200.977 us; speedup vs baseline: 1.4035x; 1.4035x over previous
//
#include <hip/hip_runtime.h>
#include <hip/hip_bf16.h>

// ---- problem constants ----
#define NN 25000
#define PP 100000
#define TT 4
#define DD 128
#define LEAKY 0.001f

#define PB 32          // propers per block
#define ROWS 128       // PB * TT rows of the MLP per block

typedef __bf16 bf16;
typedef __bf16 bf16x8 __attribute__((ext_vector_type(8)));
typedef float  f32x4  __attribute__((ext_vector_type(4)));

// ---- workspace layout (bytes) ----
#define OFF_W0SW  0u                    // 128 chunks * 1KB (fragment order)
#define OFF_W1SW  131072u               // 32 chunks * 1KB
#define OFF_W2SW  163840u               // 32 chunks * 1KB
#define OFF_W3SW  196608u               // 4 chunks * 1KB
#define OFF_WTB   200704u               // Wt[t][j] = t*W0[512]+b0, 4*128 bf16
#define OFF_W5B   201728u               // W0 rows 513..515 as bf16
#define OFF_E     202496u               // 4 tables [NN][128] bf16 = 25,600,000 B
#define WS_END    25802496u

// prep work partition (thread counts)
#define PR_W0SW  65536
#define PR_W1SW  16384
#define PR_W2SW  16384
#define PR_W3SW  2048
#define PR_WTB   512
#define PR_W5B   384
#define PR_COPY4 75000
#define PR_TOTAL (PR_W0SW + PR_W1SW + PR_W2SW + PR_W3SW + PR_WTB + PR_W5B + PR_COPY4)

__global__ __launch_bounds__(256) void prep_kernel(
    const float* __restrict__ W0, const float* __restrict__ W1,
    const float* __restrict__ W2, const float* __restrict__ W3,
    const float* __restrict__ answer, const float* __restrict__ tvec,
    const float* __restrict__ b0,
    bf16* __restrict__ W0sw, bf16* __restrict__ W1sw, bf16* __restrict__ W2sw,
    bf16* __restrict__ W3sw, bf16* __restrict__ WtB, bf16* __restrict__ W5B,
    float* __restrict__ out)
{
    int idx = blockIdx.x * 256 + threadIdx.x;
    if (idx < PR_W0SW) {
        int j = idx & 7, lane = (idx >> 3) & 63, c = idx >> 9;
        int fr = lane & 15, quad = lane >> 4;
        int kc = c & 15, iwv = c >> 4;
        int k = kc * 32 + quad * 8 + j;
        W0sw[idx] = (bf16)W0[k * 128 + iwv * 16 + fr];
        return;
    }
    idx -= PR_W0SW;
    if (idx < PR_W1SW) {
        int j = idx & 7, lane = (idx >> 3) & 63, c = idx >> 9;
        int fr = lane & 15, quad = lane >> 4;
        int kc = c & 3, nt = c >> 2;
        int k = kc * 32 + quad * 8 + j;
        W1sw[idx] = (bf16)W1[k * 128 + nt * 16 + fr];
        return;
    }
    idx -= PR_W1SW;
    if (idx < PR_W2SW) {
        int j = idx & 7, lane = (idx >> 3) & 63, c = idx >> 9;
        int fr = lane & 15, quad = lane >> 4;
        int kc = c & 3, nt = c >> 2;
        int k = kc * 32 + quad * 8 + j;
        W2sw[idx] = (bf16)W2[k * 128 + nt * 16 + fr];
        return;
    }
    idx -= PR_W2SW;
    if (idx < PR_W3SW) {
        int j = idx & 7, lane = (idx >> 3) & 63, kc = idx >> 9;
        int fr = lane & 15, quad = lane >> 4;
        int k = kc * 32 + quad * 8 + j;
        W3sw[idx] = (fr < 2) ? (bf16)W3[k * 2 + fr] : (bf16)0.0f;
        return;
    }
    idx -= PR_W3SW;
    if (idx < PR_WTB) {                 // Wt[t][j] = tvec[t]*W0[512][j] + b0[j]
        int t = idx >> 7, j = idx & 127;
        WtB[idx] = (bf16)(tvec[t] * W0[512 * 128 + j] + b0[j]);
        return;
    }
    idx -= PR_WTB;
    if (idx < PR_W5B) {                 // W0 rows 513,514,515 -> bf16
        W5B[idx] = (bf16)W0[(513 + (idx >> 7)) * 128 + (idx & 127)];
        return;
    }
    idx -= PR_W5B;
    if (idx < PR_COPY4) { ((float4*)out)[idx] = ((const float4*)answer)[idx]; }
}

// E_i[n][j] = sum_k enc[n][k]*W0[i*128+k][j]. Grid 196x4 = 784 blocks.
__global__ __launch_bounds__(512) void prep_e_kernel(
    const float* __restrict__ encoded, const bf16* __restrict__ W0sw,
    bf16* __restrict__ E)
{
    __shared__ bf16 sA[128][136];
    __shared__ bf16 sT[128][40];
    const int tid = threadIdx.x;
    const int row0 = (blockIdx.x >> 2) * 128;
    const int ntb  = blockIdx.x & 3;
    for (int c = tid; c < 4096; c += 512) {      // 128 rows x 32 float4
        int row = c >> 5, seg = c & 31;
        int rr = row0 + row; if (rr >= NN) rr = NN - 1;
        float4 v = *(const float4*)(encoded + (size_t)rr * 128 + seg * 4);
        bf16 pk[4] = {(bf16)v.x, (bf16)v.y, (bf16)v.z, (bf16)v.w};
        *(uint2*)(&sA[row][seg * 4]) = *(const uint2*)pk;
    }
    __syncthreads();
    const int wv = tid >> 6, lane = tid & 63;
    const int fr = lane & 15, quad = lane >> 4;
    const bf16* aBase = &sA[wv * 16 + fr][quad * 8];
    bf16x8 aFv[4];
    #pragma unroll
    for (int kcc = 0; kcc < 4; ++kcc) aFv[kcc] = *(const bf16x8*)(aBase + kcc * 32);
    const int orow = tid >> 2, oseg = tid & 3;
    #pragma unroll
    for (int i = 0; i < 4; ++i) {
        #pragma unroll
        for (int ntl = 0; ntl < 2; ++ntl) {
            int nt = ntb * 2 + ntl;
            f32x4 acc = {0.f, 0.f, 0.f, 0.f};
            #pragma unroll
            for (int kcc = 0; kcc < 4; ++kcc) {
                bf16x8 bF = *(const bf16x8*)(W0sw + ((size_t)nt * 16 + i * 4 + kcc) * 512 + lane * 8);
                acc = __builtin_amdgcn_mfma_f32_16x16x32_bf16(aFv[kcc], bF, acc, 0, 0, 0);
            }
            #pragma unroll
            for (int reg = 0; reg < 4; ++reg)
                sT[wv * 16 + quad * 4 + reg][ntl * 16 + fr] = (bf16)acc[reg];
        }
        __syncthreads();
        if (row0 + orow < NN)
            *(bf16x8*)(E + ((size_t)i * NN + row0 + orow) * 128 + ntb * 32 + oseg * 8) =
                *(const bf16x8*)(&sT[orow][oseg * 8]);
        __syncthreads();
    }
}

// Main: operand-swapped layer GEMMs (A = W^T frags, B = H rows) for the
// vectorized b64 epilogue — but NO wf-reload trick (R13's reload extended a
// 32-reg live range past the 64-reg cliff; compiler chose spill-at-64 ->
// 490 MB scratch traffic). Phase 4 loads W2 frags inline (transient) as in
// R12, which is proven <=64-reg clean.
__global__ __launch_bounds__(512, 4) void main_kernel(
    const float* __restrict__ coords, const int* __restrict__ propers,
    const float* __restrict__ b1, const float* __restrict__ b2,
    const float* __restrict__ b3,
    const bf16* __restrict__ E, const bf16* __restrict__ W1sw,
    const bf16* __restrict__ W2sw, const bf16* __restrict__ W3sw,
    const bf16* __restrict__ WtB, const bf16* __restrict__ W5B,
    float* __restrict__ out)
{
    __shared__ bf16 sBuf0[ROWS * 136];   // H0 then H2
    __shared__ bf16 sBuf1[ROWS * 136];   // H1
    #define SH0(r, j) sBuf0[(r) * 136 + (j)]
    #define SH1(r, j) sBuf1[(r) * 136 + (j)]
    __shared__ int   sNodes[PB][4];
    __shared__ float sSn[ROWS], sCs[ROWS], sDl[ROWS], sDh[ROWS][3];
    __shared__ float sDelta[ROWS][2];

    const int tid  = threadIdx.x;
    const int pBase = blockIdx.x * PB;
    const int wv = tid >> 6, lane = tid & 63;
    const int fr = lane & 15, quad = lane >> 4;
    const int m2 = (wv & 3) * 2;   // first of 2 row-tiles for phases 3/4
    const int nh = wv >> 2;        // N-half (cols nh*64..+63)

    // ---- phase 1: E gather + W1-frag prefetch (all 512) + geometry (tid<128) ----
    const int p  = tid >> 4, s8 = tid & 15;          // 16 threads per proper
    bf16x8 e0, e1, e2, e3;
    {
        int4 pv = *(const int4*)(propers + (pBase + p) * 4);
        if (s8 == 0) { sNodes[p][0] = pv.x; sNodes[p][1] = pv.y;
                       sNodes[p][2] = pv.z; sNodes[p][3] = pv.w; }
        e0 = *(const bf16x8*)(E + ((size_t)0 * NN + pv.x) * 128 + s8 * 8);
        e1 = *(const bf16x8*)(E + ((size_t)1 * NN + pv.y) * 128 + s8 * 8);
        e2 = *(const bf16x8*)(E + ((size_t)2 * NN + pv.z) * 128 + s8 * 8);
        e3 = *(const bf16x8*)(E + ((size_t)3 * NN + pv.w) * 128 + s8 * 8);
    }
    // w1f: W1 A-frags for phase 3 (dead afterwards — no reload; see header).
    bf16x8 w1f[16];
    {
        const bf16* w1b = W1sw + lane * 8;
        #pragma unroll
        for (int nt = 0; nt < 4; ++nt)
            #pragma unroll
            for (int kc = 0; kc < 4; ++kc)
                w1f[nt * 4 + kc] = *(const bf16x8*)(w1b + ((nh * 4 + nt) * 4 + kc) * 512);
    }
    if (tid < ROWS) {
        int r = tid, pp = r >> 2, t = r & 3;
        int4 pv = *(const int4*)(propers + (pBase + pp) * 4);
        const float* c0 = coords + pv.x * 12 + t * 3;
        const float* c1 = coords + pv.y * 12 + t * 3;
        const float* c2 = coords + pv.z * 12 + t * 3;
        const float* c3 = coords + pv.w * 12 + t * 3;
        float u1x = c1[0]-c0[0], u1y = c1[1]-c0[1], u1z = c1[2]-c0[2];
        float u2x = c2[0]-c1[0], u2y = c2[1]-c1[1], u2z = c2[2]-c1[2];
        float u3x = c3[0]-c2[0], u3y = c3[1]-c2[1], u3z = c3[2]-c2[2];
        float ax = u1y*u2z - u1z*u2y, ay = u1z*u2x - u1x*u2z, az = u1x*u2y - u1y*u2x;
        float bx = u2y*u3z - u2z*u3y, by = u2z*u3x - u2x*u3z, bz = u2x*u3y - u2y*u3x;
        float u2n = sqrtf(u2x*u2x + u2y*u2y + u2z*u2z);
        float num = u2n * (u1x*bx + u1y*by + u1z*bz);
        float den = ax*bx + ay*by + az*bz;
        float hyp = sqrtf(num*num + den*den);
        float sn, cs;
        if (hyp > 1e-30f) { float ih = 1.0f / hyp; sn = num * ih; cs = den * ih; }
        else { sn = 0.0f; cs = 1.0f; }
        float drx = c0[0]-c3[0], dry = c0[1]-c3[1], drz = c0[2]-c3[2];
        float dl = sqrtf(fmaxf(drx*drx + dry*dry + drz*drz, 1e-12f));
        float il = 1.0f / dl;
        sSn[r] = sn; sCs[r] = cs; sDl[r] = dl;
        sDh[r][0] = drx * il; sDh[r][1] = dry * il; sDh[r][2] = drz * il;
    }
    __syncthreads();   // B1: geometry + all phase-1 loads drained

    // ---- h0 = leaky(g + Wt[t] + sn*w513 + cs*w514 + dl*w515) -> SH0 ----
    {
        float g[8], w3f[8], w4f[8], w5f[8];
        #pragma unroll
        for (int j = 0; j < 8; ++j)
            g[j] = (float)e0[j] + (float)e1[j] + (float)e2[j] + (float)e3[j];
        bf16x8 w3v = *(const bf16x8*)(W5B + 0 * 128 + s8 * 8);
        bf16x8 w4v = *(const bf16x8*)(W5B + 1 * 128 + s8 * 8);
        bf16x8 w5v = *(const bf16x8*)(W5B + 2 * 128 + s8 * 8);
        #pragma unroll
        for (int j = 0; j < 8; ++j) {
            w3f[j] = (float)w3v[j]; w4f[j] = (float)w4v[j]; w5f[j] = (float)w5v[j];
        }
        #pragma unroll
        for (int t = 0; t < 4; ++t) {
            int r = p * 4 + t;
            bf16x8 wtv = *(const bf16x8*)(WtB + t * 128 + s8 * 8);
            float sn = sSn[r], cs = sCs[r], dl = sDl[r];
            bf16 hv[8];
            #pragma unroll
            for (int j = 0; j < 8; ++j) {
                float v = g[j] + (float)wtv[j] + sn * w3f[j] + cs * w4f[j] + dl * w5f[j];
                v = fmaxf(v, LEAKY * v);
                hv[j] = (bf16)v;
            }
            *(bf16x8*)(&SH0(r, s8 * 8)) = *(const bf16x8*)hv;
        }
    }
    __syncthreads();   // B2: H0 ready

    // ---- phase 3: h1 = leaky(h0 @ W1 + b1); A=w1f (W1^T), B=H0 rows ----
    #pragma unroll
    for (int s = 0; s < 2; ++s) {
        f32x4 hacc[4];
        #pragma unroll
        for (int nt = 0; nt < 4; ++nt) hacc[nt] = (f32x4){0.f,0.f,0.f,0.f};
        const bf16* bRow = &SH0((m2 + s) * 16 + fr, quad * 8);
        #pragma unroll
        for (int kc = 0; kc < 4; ++kc) {
            bf16x8 bF = *(const bf16x8*)(bRow + kc * 32);
            #pragma unroll
            for (int nt = 0; nt < 4; ++nt)
                hacc[nt] = __builtin_amdgcn_mfma_f32_16x16x32_bf16(w1f[nt * 4 + kc], bF, hacc[nt], 0, 0, 0);
        }
        int r = (m2 + s) * 16 + fr;          // D col = H row
        #pragma unroll
        for (int nt = 0; nt < 4; ++nt) {
            int j0 = (nh * 4 + nt) * 16 + quad * 4;   // D rows = 4 consecutive j
            float4 bb = *(const float4*)(b1 + j0);
            bf16 hv[4];
            float v0 = hacc[nt][0] + bb.x; v0 = fmaxf(v0, LEAKY * v0); hv[0] = (bf16)v0;
            float v1 = hacc[nt][1] + bb.y; v1 = fmaxf(v1, LEAKY * v1); hv[1] = (bf16)v1;
            float v2 = hacc[nt][2] + bb.z; v2 = fmaxf(v2, LEAKY * v2); hv[2] = (bf16)v2;
            float v3 = hacc[nt][3] + bb.w; v3 = fmaxf(v3, LEAKY * v3); hv[3] = (bf16)v3;
            *(uint2*)(&SH1(r, j0)) = *(const uint2*)hv;
        }
    }
    __syncthreads();   // B3: H1 ready, H0 reads complete

    // ---- phase 4: h2 = leaky(h1 @ W2 + b2); A=W2^T frags (inline loads), B=H1 rows ----
    #pragma unroll
    for (int s = 0; s < 2; ++s) {
        f32x4 hacc[4];
        #pragma unroll
        for (int nt = 0; nt < 4; ++nt) hacc[nt] = (f32x4){0.f,0.f,0.f,0.f};
        const bf16* bRow = &SH1((m2 + s) * 16 + fr, quad * 8);
        const bf16* w2b = W2sw + lane * 8;
        #pragma unroll
        for (int kc = 0; kc < 4; ++kc) {
            bf16x8 bF = *(const bf16x8*)(bRow + kc * 32);
            #pragma unroll
            for (int nt = 0; nt < 4; ++nt) {
                bf16x8 aF = *(const bf16x8*)(w2b + ((nh * 4 + nt) * 4 + kc) * 512);
                hacc[nt] = __builtin_amdgcn_mfma_f32_16x16x32_bf16(aF, bF, hacc[nt], 0, 0, 0);
            }
        }
        int r = (m2 + s) * 16 + fr;
        #pragma unroll
        for (int nt = 0; nt < 4; ++nt) {
            int j0 = (nh * 4 + nt) * 16 + quad * 4;
            float4 bb = *(const float4*)(b2 + j0);
            bf16 hv[4];
            float v0 = hacc[nt][0] + bb.x; v0 = fmaxf(v0, LEAKY * v0); hv[0] = (bf16)v0;
            float v1 = hacc[nt][1] + bb.y; v1 = fmaxf(v1, LEAKY * v1); hv[1] = (bf16)v1;
            float v2 = hacc[nt][2] + bb.z; v2 = fmaxf(v2, LEAKY * v2); hv[2] = (bf16)v2;
            float v3 = hacc[nt][3] + bb.w; v3 = fmaxf(v3, LEAKY * v3); hv[3] = (bf16)v3;
            *(uint2*)(&SH0(r, j0)) = *(const uint2*)hv;
        }
    }
    __syncthreads();   // B4: H2 ready

    // ---- phase 5: delta = h2 @ W3 + b3; A=W3^T frags, B=H2 rows ----
    {
        f32x4 dacc = {0.f,0.f,0.f,0.f};
        const bf16* bRow = &SH0(wv * 16 + fr, quad * 8);
        const bf16* w3b = W3sw + lane * 8;
        #pragma unroll
        for (int kc = 0; kc < 4; ++kc) {
            bf16x8 aF = *(const bf16x8*)(w3b + kc * 512);
            bf16x8 bF = *(const bf16x8*)(bRow + kc * 32);
            dacc = __builtin_amdgcn_mfma_f32_16x16x32_bf16(aF, bF, dacc, 0, 0, 0);
        }
        if (quad == 0) {               // D rows 0,1 (= delta cols) in regs 0,1
            int r = wv * 16 + fr;
            sDelta[r][0] = dacc[0] + b3[0];
            sDelta[r][1] = dacc[1] + b3[1];
        }
    }
    __syncthreads();   // B5: delta ready

    // ---- phase 6: scatter-add (6 atomics per row, 768 total) ----
    for (int idx = tid; idx < ROWS * 6; idx += 512) {
        int r = idx / 6, c = idx % 6;
        int pp = r >> 2, t = r & 3;
        int side = c / 3, ax = c % 3;
        int node = sNodes[pp][side ? 3 : 0];
        float dval = side ? 0.5f * sDelta[r][1] : -0.5f * sDelta[r][0];
        atomicAdd(out + node * 12 + t * 3 + ax, dval * sDh[r][ax]);
    }
    #undef SH0
    #undef SH1
}

extern "C" void kernel_launch(void* const* d_in, const int* in_sizes, int n_in,
                              void* d_out, int out_size, void* d_ws, size_t ws_size,
                              hipStream_t stream) {
    const float* coords  = (const float*)d_in[0];
    const int*   propers = (const int*)d_in[1];
    const float* encoded = (const float*)d_in[2];
    const float* tvec    = (const float*)d_in[3];
    const float* answer  = (const float*)d_in[4];
    const float* W0 = (const float*)d_in[5];
    const float* b0 = (const float*)d_in[6];
    const float* W1 = (const float*)d_in[7];
    const float* b1 = (const float*)d_in[8];
    const float* W2 = (const float*)d_in[9];
    const float* b2 = (const float*)d_in[10];
    const float* W3 = (const float*)d_in[11];
    const float* b3 = (const float*)d_in[12];
    float* out = (float*)d_out;
    char* ws = (char*)d_ws;
    bf16* W0sw = (bf16*)(ws + OFF_W0SW);
    bf16* W1sw = (bf16*)(ws + OFF_W1SW);
    bf16* W2sw = (bf16*)(ws + OFF_W2SW);
    bf16* W3sw = (bf16*)(ws + OFF_W3SW);
    bf16* WtB  = (bf16*)(ws + OFF_WTB);
    bf16* W5B  = (bf16*)(ws + OFF_W5B);
    bf16* E    = (bf16*)(ws + OFF_E);

    int prep_blocks = (PR_TOTAL + 255) / 256;
    prep_kernel<<<prep_blocks, 256, 0, stream>>>(W0, W1, W2, W3, answer, tvec, b0,
                                                 W0sw, W1sw, W2sw, W3sw, WtB, W5B, out);
    prep_e_kernel<<<196 * 4, 512, 0, stream>>>(encoded, W0sw, E);
    main_kernel<<<PP / PB, 512, 0, stream>>>(coords, propers, b1, b2, b3,
                                             E, W1sw, W2sw, W3sw, WtB, W5B, out);
}

// Round 15
// 193.917 us; speedup vs baseline: 1.4546x; 1.0364x over previous
//
#include <hip/hip_runtime.h>
#include <hip/hip_bf16.h>

// ---- problem constants ----
#define NN 25000
#define PP 100000
#define TT 4
#define DD 128
#define LEAKY 0.001f

#define PB 32          // propers per block
#define ROWS 128       // PB * TT rows of the MLP per block

typedef __bf16 bf16;
typedef __bf16 bf16x8 __attribute__((ext_vector_type(8)));
typedef float  f32x4  __attribute__((ext_vector_type(4)));

// ---- workspace layout (bytes) ----
#define OFF_W0SW  0u                    // 128 chunks * 1KB (fragment order)
#define OFF_W1SW  131072u               // 32 chunks * 1KB
#define OFF_W2SW  163840u               // 32 chunks * 1KB
#define OFF_W3SW  196608u               // 4 chunks * 1KB
#define OFF_WTB   200704u               // Wt[t][j] = t*W0[512]+b0, 4*128 bf16
#define OFF_W5B   201728u               // W0 rows 513..515 as bf16
#define OFF_E     202496u               // 4 tables [NN][128] bf16 = 25,600,000 B
#define WS_END    25802496u

// prep work partition (thread counts)
#define PR_W0SW  65536
#define PR_W1SW  16384
#define PR_W2SW  16384
#define PR_W3SW  2048
#define PR_WTB   512
#define PR_W5B   384
#define PR_COPY4 75000
#define PR_TOTAL (PR_W0SW + PR_W1SW + PR_W2SW + PR_W3SW + PR_WTB + PR_W5B + PR_COPY4)

__global__ __launch_bounds__(256) void prep_kernel(
    const float* __restrict__ W0, const float* __restrict__ W1,
    const float* __restrict__ W2, const float* __restrict__ W3,
    const float* __restrict__ answer, const float* __restrict__ tvec,
    const float* __restrict__ b0,
    bf16* __restrict__ W0sw, bf16* __restrict__ W1sw, bf16* __restrict__ W2sw,
    bf16* __restrict__ W3sw, bf16* __restrict__ WtB, bf16* __restrict__ W5B,
    float* __restrict__ out)
{
    int idx = blockIdx.x * 256 + threadIdx.x;
    if (idx < PR_W0SW) {
        int j = idx & 7, lane = (idx >> 3) & 63, c = idx >> 9;
        int fr = lane & 15, quad = lane >> 4;
        int kc = c & 15, iwv = c >> 4;
        int k = kc * 32 + quad * 8 + j;
        W0sw[idx] = (bf16)W0[k * 128 + iwv * 16 + fr];
        return;
    }
    idx -= PR_W0SW;
    if (idx < PR_W1SW) {
        int j = idx & 7, lane = (idx >> 3) & 63, c = idx >> 9;
        int fr = lane & 15, quad = lane >> 4;
        int kc = c & 3, nt = c >> 2;
        int k = kc * 32 + quad * 8 + j;
        W1sw[idx] = (bf16)W1[k * 128 + nt * 16 + fr];
        return;
    }
    idx -= PR_W1SW;
    if (idx < PR_W2SW) {
        int j = idx & 7, lane = (idx >> 3) & 63, c = idx >> 9;
        int fr = lane & 15, quad = lane >> 4;
        int kc = c & 3, nt = c >> 2;
        int k = kc * 32 + quad * 8 + j;
        W2sw[idx] = (bf16)W2[k * 128 + nt * 16 + fr];
        return;
    }
    idx -= PR_W2SW;
    if (idx < PR_W3SW) {
        int j = idx & 7, lane = (idx >> 3) & 63, kc = idx >> 9;
        int fr = lane & 15, quad = lane >> 4;
        int k = kc * 32 + quad * 8 + j;
        W3sw[idx] = (fr < 2) ? (bf16)W3[k * 2 + fr] : (bf16)0.0f;
        return;
    }
    idx -= PR_W3SW;
    if (idx < PR_WTB) {                 // Wt[t][j] = tvec[t]*W0[512][j] + b0[j]
        int t = idx >> 7, j = idx & 127;
        WtB[idx] = (bf16)(tvec[t] * W0[512 * 128 + j] + b0[j]);
        return;
    }
    idx -= PR_WTB;
    if (idx < PR_W5B) {                 // W0 rows 513,514,515 -> bf16
        W5B[idx] = (bf16)W0[(513 + (idx >> 7)) * 128 + (idx & 127)];
        return;
    }
    idx -= PR_W5B;
    if (idx < PR_COPY4) { ((float4*)out)[idx] = ((const float4*)answer)[idx]; }
}

// E_i[n][j] = sum_k enc[n][k]*W0[i*128+k][j]. Grid 196x4 = 784 blocks.
__global__ __launch_bounds__(512) void prep_e_kernel(
    const float* __restrict__ encoded, const bf16* __restrict__ W0sw,
    bf16* __restrict__ E)
{
    __shared__ bf16 sA[128][136];
    __shared__ bf16 sT[128][40];
    const int tid = threadIdx.x;
    const int row0 = (blockIdx.x >> 2) * 128;
    const int ntb  = blockIdx.x & 3;
    for (int c = tid; c < 4096; c += 512) {      // 128 rows x 32 float4
        int row = c >> 5, seg = c & 31;
        int rr = row0 + row; if (rr >= NN) rr = NN - 1;
        float4 v = *(const float4*)(encoded + (size_t)rr * 128 + seg * 4);
        bf16 pk[4] = {(bf16)v.x, (bf16)v.y, (bf16)v.z, (bf16)v.w};
        *(uint2*)(&sA[row][seg * 4]) = *(const uint2*)pk;
    }
    __syncthreads();
    const int wv = tid >> 6, lane = tid & 63;
    const int fr = lane & 15, quad = lane >> 4;
    const bf16* aBase = &sA[wv * 16 + fr][quad * 8];
    bf16x8 aFv[4];
    #pragma unroll
    for (int kcc = 0; kcc < 4; ++kcc) aFv[kcc] = *(const bf16x8*)(aBase + kcc * 32);
    const int orow = tid >> 2, oseg = tid & 3;
    #pragma unroll
    for (int i = 0; i < 4; ++i) {
        #pragma unroll
        for (int ntl = 0; ntl < 2; ++ntl) {
            int nt = ntb * 2 + ntl;
            f32x4 acc = {0.f, 0.f, 0.f, 0.f};
            #pragma unroll
            for (int kcc = 0; kcc < 4; ++kcc) {
                bf16x8 bF = *(const bf16x8*)(W0sw + ((size_t)nt * 16 + i * 4 + kcc) * 512 + lane * 8);
                acc = __builtin_amdgcn_mfma_f32_16x16x32_bf16(aFv[kcc], bF, acc, 0, 0, 0);
            }
            #pragma unroll
            for (int reg = 0; reg < 4; ++reg)
                sT[wv * 16 + quad * 4 + reg][ntl * 16 + fr] = (bf16)acc[reg];
        }
        __syncthreads();
        if (row0 + orow < NN)
            *(bf16x8*)(E + ((size_t)i * NN + row0 + orow) * 128 + ntb * 32 + oseg * 8) =
                *(const bf16x8*)(&sT[orow][oseg * 8]);
        __syncthreads();
    }
}

// Main (R12-proven config, session best): E-gather h0 + MFMA layers with
// A=activations/B=weights (the R14 operand swap cut VALU but added 4-way
// bank conflicts on epilogue stores — net negative; reverted). W1 frags
// register-prefetched in phase 1 only (the R13 W2 reload trick tipped the
// 64-VGPR cliff into 490 MB of spill traffic — never extend frag lifetimes).
__global__ __launch_bounds__(512, 4) void main_kernel(
    const float* __restrict__ coords, const int* __restrict__ propers,
    const float* __restrict__ b1, const float* __restrict__ b2,
    const float* __restrict__ b3,
    const bf16* __restrict__ E, const bf16* __restrict__ W1sw,
    const bf16* __restrict__ W2sw, const bf16* __restrict__ W3sw,
    const bf16* __restrict__ WtB, const bf16* __restrict__ W5B,
    float* __restrict__ out)
{
    __shared__ bf16 sBuf0[ROWS * 136];   // H0 then H2
    __shared__ bf16 sBuf1[ROWS * 136];   // H1
    #define SH0(r, j) sBuf0[(r) * 136 + (j)]
    #define SH1(r, j) sBuf1[(r) * 136 + (j)]
    __shared__ int   sNodes[PB][4];
    __shared__ float sSn[ROWS], sCs[ROWS], sDl[ROWS], sDh[ROWS][3];
    __shared__ float sDelta[ROWS][2];

    const int tid  = threadIdx.x;
    const int pBase = blockIdx.x * PB;
    const int wv = tid >> 6, lane = tid & 63;
    const int fr = lane & 15, quad = lane >> 4;
    const int m2 = (wv & 3) * 2;   // first of 2 M-tiles for phases 3/4
    const int nh = wv >> 2;        // N-half (cols nh*64..+63)

    // ---- phase 1: E gather + W1-frag prefetch (all 512) + geometry (tid<128) ----
    const int p  = tid >> 4, s8 = tid & 15;          // 16 threads per proper
    bf16x8 e0, e1, e2, e3;
    {
        int4 pv = *(const int4*)(propers + (pBase + p) * 4);
        if (s8 == 0) { sNodes[p][0] = pv.x; sNodes[p][1] = pv.y;
                       sNodes[p][2] = pv.z; sNodes[p][3] = pv.w; }
        e0 = *(const bf16x8*)(E + ((size_t)0 * NN + pv.x) * 128 + s8 * 8);
        e1 = *(const bf16x8*)(E + ((size_t)1 * NN + pv.y) * 128 + s8 * 8);
        e2 = *(const bf16x8*)(E + ((size_t)2 * NN + pv.z) * 128 + s8 * 8);
        e3 = *(const bf16x8*)(E + ((size_t)3 * NN + pv.w) * 128 + s8 * 8);
    }
    // W1 B-frags for phase 3: 16 x 16B = 64 VGPRs, loaded now so their
    // latency overlaps the E-gather drain at B1.
    bf16x8 w1f[16];
    {
        const bf16* w1b = W1sw + lane * 8;
        #pragma unroll
        for (int nt = 0; nt < 4; ++nt)
            #pragma unroll
            for (int kc = 0; kc < 4; ++kc)
                w1f[nt * 4 + kc] = *(const bf16x8*)(w1b + ((nh * 4 + nt) * 4 + kc) * 512);
    }
    if (tid < ROWS) {
        int r = tid, pp = r >> 2, t = r & 3;
        int4 pv = *(const int4*)(propers + (pBase + pp) * 4);
        const float* c0 = coords + pv.x * 12 + t * 3;
        const float* c1 = coords + pv.y * 12 + t * 3;
        const float* c2 = coords + pv.z * 12 + t * 3;
        const float* c3 = coords + pv.w * 12 + t * 3;
        float u1x = c1[0]-c0[0], u1y = c1[1]-c0[1], u1z = c1[2]-c0[2];
        float u2x = c2[0]-c1[0], u2y = c2[1]-c1[1], u2z = c2[2]-c1[2];
        float u3x = c3[0]-c2[0], u3y = c3[1]-c2[1], u3z = c3[2]-c2[2];
        float ax = u1y*u2z - u1z*u2y, ay = u1z*u2x - u1x*u2z, az = u1x*u2y - u1y*u2x;
        float bx = u2y*u3z - u2z*u3y, by = u2z*u3x - u2x*u3z, bz = u2x*u3y - u2y*u3x;
        float u2n = sqrtf(u2x*u2x + u2y*u2y + u2z*u2z);
        float num = u2n * (u1x*bx + u1y*by + u1z*bz);
        float den = ax*bx + ay*by + az*bz;
        float hyp = sqrtf(num*num + den*den);
        float sn, cs;
        if (hyp > 1e-30f) { float ih = 1.0f / hyp; sn = num * ih; cs = den * ih; }
        else { sn = 0.0f; cs = 1.0f; }
        float drx = c0[0]-c3[0], dry = c0[1]-c3[1], drz = c0[2]-c3[2];
        float dl = sqrtf(fmaxf(drx*drx + dry*dry + drz*drz, 1e-12f));
        float il = 1.0f / dl;
        sSn[r] = sn; sCs[r] = cs; sDl[r] = dl;
        sDh[r][0] = drx * il; sDh[r][1] = dry * il; sDh[r][2] = drz * il;
    }
    __syncthreads();   // B1: geometry + all phase-1 loads drained

    // ---- h0 = leaky(g + Wt[t] + sn*w513 + cs*w514 + dl*w515) -> SH0 ----
    {
        float g[8], w3f[8], w4f[8], w5f[8];
        #pragma unroll
        for (int j = 0; j < 8; ++j)
            g[j] = (float)e0[j] + (float)e1[j] + (float)e2[j] + (float)e3[j];
        bf16x8 w3v = *(const bf16x8*)(W5B + 0 * 128 + s8 * 8);
        bf16x8 w4v = *(const bf16x8*)(W5B + 1 * 128 + s8 * 8);
        bf16x8 w5v = *(const bf16x8*)(W5B + 2 * 128 + s8 * 8);
        #pragma unroll
        for (int j = 0; j < 8; ++j) {   // converted once, not per-t
            w3f[j] = (float)w3v[j]; w4f[j] = (float)w4v[j]; w5f[j] = (float)w5v[j];
        }
        #pragma unroll
        for (int t = 0; t < 4; ++t) {
            int r = p * 4 + t;
            bf16x8 wtv = *(const bf16x8*)(WtB + t * 128 + s8 * 8);
            float sn = sSn[r], cs = sCs[r], dl = sDl[r];
            bf16 hv[8];
            #pragma unroll
            for (int j = 0; j < 8; ++j) {
                float v = g[j] + (float)wtv[j] + sn * w3f[j] + cs * w4f[j] + dl * w5f[j];
                v = fmaxf(v, LEAKY * v);
                hv[j] = (bf16)v;
            }
            *(bf16x8*)(&SH0(r, s8 * 8)) = *(const bf16x8*)hv;
        }
    }
    __syncthreads();   // B2: H0 ready

    // ---- phase 3: h1 = leaky(h0 @ W1 + b1); B-frags from registers ----
    #pragma unroll
    for (int s = 0; s < 2; ++s) {
        f32x4 hacc[4];
        #pragma unroll
        for (int nt = 0; nt < 4; ++nt) hacc[nt] = (f32x4){0.f,0.f,0.f,0.f};
        const bf16* aRow = &SH0((m2 + s) * 16 + fr, quad * 8);
        #pragma unroll
        for (int kc = 0; kc < 4; ++kc) {
            bf16x8 aF = *(const bf16x8*)(aRow + kc * 32);
            #pragma unroll
            for (int nt = 0; nt < 4; ++nt)
                hacc[nt] = __builtin_amdgcn_mfma_f32_16x16x32_bf16(aF, w1f[nt * 4 + kc], hacc[nt], 0, 0, 0);
        }
        #pragma unroll
        for (int nt = 0; nt < 4; ++nt) {
            int j = (nh * 4 + nt) * 16 + fr;
            float bb = b1[j];
            #pragma unroll
            for (int reg = 0; reg < 4; ++reg) {
                int r = (m2 + s) * 16 + quad * 4 + reg;
                float v = hacc[nt][reg] + bb;
                v = fmaxf(v, LEAKY * v);
                SH1(r, j) = (bf16)v;
            }
        }
    }
    __syncthreads();   // B3: H1 ready, H0 reads complete

    // ---- phase 4: h2 = leaky(h1 @ W2 + b2); read SH1, write SH0 ----
    #pragma unroll
    for (int s = 0; s < 2; ++s) {
        f32x4 hacc[4];
        #pragma unroll
        for (int nt = 0; nt < 4; ++nt) hacc[nt] = (f32x4){0.f,0.f,0.f,0.f};
        const bf16* aRow = &SH1((m2 + s) * 16 + fr, quad * 8);
        const bf16* w2b = W2sw + lane * 8;
        #pragma unroll
        for (int kc = 0; kc < 4; ++kc) {
            bf16x8 aF = *(const bf16x8*)(aRow + kc * 32);
            #pragma unroll
            for (int nt = 0; nt < 4; ++nt) {
                bf16x8 bF = *(const bf16x8*)(w2b + ((nh * 4 + nt) * 4 + kc) * 512);
                hacc[nt] = __builtin_amdgcn_mfma_f32_16x16x32_bf16(aF, bF, hacc[nt], 0, 0, 0);
            }
        }
        #pragma unroll
        for (int nt = 0; nt < 4; ++nt) {
            int j = (nh * 4 + nt) * 16 + fr;
            float bb = b2[j];
            #pragma unroll
            for (int reg = 0; reg < 4; ++reg) {
                int r = (m2 + s) * 16 + quad * 4 + reg;
                float v = hacc[nt][reg] + bb;
                v = fmaxf(v, LEAKY * v);
                SH0(r, j) = (bf16)v;
            }
        }
    }
    __syncthreads();   // B4: H2 ready

    // ---- phase 5: delta = h2 @ W3 + b3 (zero-padded to 16 cols); all 8 waves ----
    {
        f32x4 dacc = {0.f,0.f,0.f,0.f};
        const bf16* aRow = &SH0(wv * 16 + fr, quad * 8);
        const bf16* w3b = W3sw + lane * 8;
        #pragma unroll
        for (int kc = 0; kc < 4; ++kc) {
            bf16x8 aF = *(const bf16x8*)(aRow + kc * 32);
            bf16x8 bF = *(const bf16x8*)(w3b + kc * 512);
            dacc = __builtin_amdgcn_mfma_f32_16x16x32_bf16(aF, bF, dacc, 0, 0, 0);
        }
        if (fr < 2) {
            float bb = b3[fr];
            #pragma unroll
            for (int reg = 0; reg < 4; ++reg)
                sDelta[wv * 16 + quad * 4 + reg][fr] = dacc[reg] + bb;
        }
    }
    __syncthreads();   // B5: delta ready

    // ---- phase 6: scatter-add (6 atomics per row, 768 total) ----
    for (int idx = tid; idx < ROWS * 6; idx += 512) {
        int r = idx / 6, c = idx % 6;
        int pp = r >> 2, t = r & 3;
        int side = c / 3, ax = c % 3;
        int node = sNodes[pp][side ? 3 : 0];
        float dval = side ? 0.5f * sDelta[r][1] : -0.5f * sDelta[r][0];
        atomicAdd(out + node * 12 + t * 3 + ax, dval * sDh[r][ax]);
    }
    #undef SH0
    #undef SH1
}

extern "C" void kernel_launch(void* const* d_in, const int* in_sizes, int n_in,
                              void* d_out, int out_size, void* d_ws, size_t ws_size,
                              hipStream_t stream) {
    const float* coords  = (const float*)d_in[0];
    const int*   propers = (const int*)d_in[1];
    const float* encoded = (const float*)d_in[2];
    const float* tvec    = (const float*)d_in[3];
    const float* answer  = (const float*)d_in[4];
    const float* W0 = (const float*)d_in[5];
    const float* b0 = (const float*)d_in[6];
    const float* W1 = (const float*)d_in[7];
    const float* b1 = (const float*)d_in[8];
    const float* W2 = (const float*)d_in[9];
    const float* b2 = (const float*)d_in[10];
    const float* W3 = (const float*)d_in[11];
    const float* b3 = (const float*)d_in[12];
    float* out = (float*)d_out;
    char* ws = (char*)d_ws;
    bf16* W0sw = (bf16*)(ws + OFF_W0SW);
    bf16* W1sw = (bf16*)(ws + OFF_W1SW);
    bf16* W2sw = (bf16*)(ws + OFF_W2SW);
    bf16* W3sw = (bf16*)(ws + OFF_W3SW);
    bf16* WtB  = (bf16*)(ws + OFF_WTB);
    bf16* W5B  = (bf16*)(ws + OFF_W5B);
    bf16* E    = (bf16*)(ws + OFF_E);

    int prep_blocks = (PR_TOTAL + 255) / 256;
    prep_kernel<<<prep_blocks, 256, 0, stream>>>(W0, W1, W2, W3, answer, tvec, b0,
                                                 W0sw, W1sw, W2sw, W3sw, WtB, W5B, out);
    prep_e_kernel<<<196 * 4, 512, 0, stream>>>(encoded, W0sw, E);
    main_kernel<<<PP / PB, 512, 0, stream>>>(coords, propers, b1, b2, b3,
                                             E, W1sw, W2sw, W3sw, WtB, W5B, out);
}